// Round 1
// baseline (306.986 us; speedup 1.0000x reference)
//
#include <hip/hip_runtime.h>

#define LEAKY_SLOPE 0.2f

constexpr int B_   = 16;
constexpr int N_   = 4096;
constexpr int K_   = 4096;
constexpr int IN_  = 16384;   // K + 3K
constexpr int H1_  = 1024;
constexpr int H2_  = 512;
constexpr int OUT_ = 256;

// encode tiling: NCH chunks over N, NPC points per chunk, 4 k's per thread
constexpr int NCH = 8;
constexpr int NPC = N_ / NCH;   // 512 points -> 8KB LDS
constexpr int KPT = 4;          // k per thread
constexpr int KTB = 256 * KPT;  // 1024 k per block

// -------------------------------------------------------------------------
// Kernel 1: per-(batch, k-tile, n-chunk) partial argmin of d2.
// d2 mirrors numpy: d2 = (bn + pn) - 2*cross, cross = fma chain over d.
// -------------------------------------------------------------------------
__global__ __launch_bounds__(256) void enc_partial(
    const float* __restrict__ pc, const float* __restrict__ basis,
    float* __restrict__ d2p, int* __restrict__ idxp)
{
#pragma clang fp contract(off)
    __shared__ float4 pts[NPC];
    const int kt = blockIdx.x;   // k-tile (K_/KTB)
    const int b  = blockIdx.y;   // batch
    const int c  = blockIdx.z;   // n-chunk
    const int n0 = c * NPC;

    const float* pcb = pc + ((size_t)b * N_ + n0) * 3;
    for (int n = threadIdx.x; n < NPC; n += 256) {
        float x = pcb[n * 3 + 0];
        float y = pcb[n * 3 + 1];
        float z = pcb[n * 3 + 2];
        float pn = (x * x + y * y) + z * z;   // numpy order, no fma
        pts[n] = make_float4(x, y, z, pn);
    }
    __syncthreads();

    const int k0 = kt * KTB + (int)threadIdx.x;
    float bx[KPT], by[KPT], bz[KPT], bn[KPT], best[KPT];
    int   bi[KPT];
#pragma unroll
    for (int q = 0; q < KPT; ++q) {
        int k = k0 + q * 256;
        bx[q] = basis[k * 3 + 0];
        by[q] = basis[k * 3 + 1];
        bz[q] = basis[k * 3 + 2];
        bn[q] = (bx[q] * bx[q] + by[q] * by[q]) + bz[q] * bz[q];
        best[q] = 3.4028235e38f;
        bi[q] = 0;
    }

#pragma unroll 2
    for (int n = 0; n < NPC; ++n) {
        float4 p = pts[n];
#pragma unroll
        for (int q = 0; q < KPT; ++q) {
            float cr = __builtin_fmaf(bz[q], p.z,
                        __builtin_fmaf(by[q], p.y, bx[q] * p.x));
            float t  = bn[q] + p.w;
            // t - 2*cr : 2*cr is exact, so fused form == numpy's two-op form
            float d2 = __builtin_fmaf(-2.0f, cr, t);
            if (d2 < best[q]) { best[q] = d2; bi[q] = n0 + n; }  // strict < : first-min
        }
    }

#pragma unroll
    for (int q = 0; q < KPT; ++q) {
        int g = b * K_ + (k0 + q * 256);
        d2p[(size_t)c * (B_ * K_) + g]  = best[q];
        idxp[(size_t)c * (B_ * K_) + g] = bi[q];
    }
}

// -------------------------------------------------------------------------
// Kernel 2: combine chunk partials (ascending chunk, strict <  => first-min),
// gather nearest point, write bps feature row (to d_out) and transposed
// feature bpsT[i][16] for the GEMM.
// -------------------------------------------------------------------------
__global__ __launch_bounds__(256) void enc_finish(
    const float* __restrict__ pc, const float* __restrict__ basis,
    const float* __restrict__ d2p, const int* __restrict__ idxp,
    float* __restrict__ bps_out, float* __restrict__ bpsT)
{
#pragma clang fp contract(off)
    const int t = blockIdx.x * 256 + (int)threadIdx.x;   // 0 .. B*K-1
    const int b = t >> 12;
    const int k = t & (K_ - 1);

    float best = d2p[t];
    int   bi   = idxp[t];
    for (int c = 1; c < NCH; ++c) {
        float d = d2p[(size_t)c * (B_ * K_) + t];
        if (d < best) { best = d; bi = idxp[(size_t)c * (B_ * K_) + t]; }
    }

    const float* p = pc + ((size_t)b * N_ + bi) * 3;
    float dx = p[0] - basis[k * 3 + 0];
    float dy = p[1] - basis[k * 3 + 1];
    float dz = p[2] - basis[k * 3 + 2];
    float dist = sqrtf((dx * dx + dy * dy) + dz * dz);

    float* row = bps_out + (size_t)b * IN_;
    row[k]              = dist;
    row[K_ + 3 * k + 0] = dx;
    row[K_ + 3 * k + 1] = dy;
    row[K_ + 3 * k + 2] = dz;

    bpsT[(size_t)k * B_ + b]                = dist;
    bpsT[(size_t)(K_ + 3 * k + 0) * B_ + b] = dx;
    bpsT[(size_t)(K_ + 3 * k + 1) * B_ + b] = dy;
    bpsT[(size_t)(K_ + 3 * k + 2) * B_ + b] = dz;
}

// -------------------------------------------------------------------------
// MLP GEMM: AT is [Kdim][16] (wave-uniform rows -> s_load), W is [Kdim][Ncols]
// row-major (coalesced across j). Each thread owns one column j, 16 batch
// accumulators. i-dimension split across blockIdx.y -> partial sums.
// -------------------------------------------------------------------------
__global__ __launch_bounds__(128) void mlp_gemm(
    const float* __restrict__ AT, const float* __restrict__ W,
    float* __restrict__ part, int Ncols, int ilen)
{
    const int j  = blockIdx.x * 128 + (int)threadIdx.x;
    const int i0 = blockIdx.y * ilen;

    float acc[16];
#pragma unroll
    for (int r = 0; r < 16; ++r) acc[r] = 0.0f;

    const float*  Wp = W + (size_t)i0 * Ncols + j;
    const float4* Ap = (const float4*)(AT + (size_t)i0 * 16);

#pragma unroll 2
    for (int i = 0; i < ilen; ++i) {
        float  w  = Wp[(size_t)i * Ncols];
        float4 a0 = Ap[i * 4 + 0];
        float4 a1 = Ap[i * 4 + 1];
        float4 a2 = Ap[i * 4 + 2];
        float4 a3 = Ap[i * 4 + 3];
        acc[0]  = __builtin_fmaf(a0.x, w, acc[0]);
        acc[1]  = __builtin_fmaf(a0.y, w, acc[1]);
        acc[2]  = __builtin_fmaf(a0.z, w, acc[2]);
        acc[3]  = __builtin_fmaf(a0.w, w, acc[3]);
        acc[4]  = __builtin_fmaf(a1.x, w, acc[4]);
        acc[5]  = __builtin_fmaf(a1.y, w, acc[5]);
        acc[6]  = __builtin_fmaf(a1.z, w, acc[6]);
        acc[7]  = __builtin_fmaf(a1.w, w, acc[7]);
        acc[8]  = __builtin_fmaf(a2.x, w, acc[8]);
        acc[9]  = __builtin_fmaf(a2.y, w, acc[9]);
        acc[10] = __builtin_fmaf(a2.z, w, acc[10]);
        acc[11] = __builtin_fmaf(a2.w, w, acc[11]);
        acc[12] = __builtin_fmaf(a3.x, w, acc[12]);
        acc[13] = __builtin_fmaf(a3.y, w, acc[13]);
        acc[14] = __builtin_fmaf(a3.z, w, acc[14]);
        acc[15] = __builtin_fmaf(a3.w, w, acc[15]);
    }

    float4* p4 = (float4*)(part + ((size_t)blockIdx.y * Ncols + j) * 16);
    p4[0] = make_float4(acc[0],  acc[1],  acc[2],  acc[3]);
    p4[1] = make_float4(acc[4],  acc[5],  acc[6],  acc[7]);
    p4[2] = make_float4(acc[8],  acc[9],  acc[10], acc[11]);
    p4[3] = make_float4(acc[12], acc[13], acc[14], acc[15]);
}

// -------------------------------------------------------------------------
// Reduce partials + bias + (leaky) -> transposed activations [j][16], or
// final row-major output [16][Ncols].
// -------------------------------------------------------------------------
__global__ __launch_bounds__(256) void mlp_reduce(
    const float* __restrict__ part, const float* __restrict__ bias,
    float* __restrict__ outT, float* __restrict__ out_rm,
    int Ncols, int nchunks, int do_leaky)
{
    const int p = blockIdx.x * 256 + (int)threadIdx.x;   // j*16 + r
    const int total = Ncols * 16;
    float s = 0.0f;
    for (int c = 0; c < nchunks; ++c) s += part[(size_t)c * total + p];
    const int j = p >> 4;
    const int r = p & 15;
    s += bias[j];
    if (do_leaky) s = (s >= 0.0f) ? s : LEAKY_SLOPE * s;
    if (outT)   outT[p] = s;
    if (out_rm) out_rm[(size_t)r * Ncols + j] = s;
}

// -------------------------------------------------------------------------
extern "C" void kernel_launch(void* const* d_in, const int* in_sizes, int n_in,
                              void* d_out, int out_size, void* d_ws, size_t ws_size,
                              hipStream_t stream)
{
    const float* pc    = (const float*)d_in[0];
    const float* basis = (const float*)d_in[1];
    const float* W1    = (const float*)d_in[2];
    const float* b1    = (const float*)d_in[3];
    const float* W2    = (const float*)d_in[4];
    const float* b2    = (const float*)d_in[5];
    const float* W3    = (const float*)d_in[6];
    const float* b3    = (const float*)d_in[7];

    float* out   = (float*)d_out;
    float* gfeat = out;                 // [16][256]
    float* bps   = out + B_ * OUT_;     // [16][16384]

    char* ws = (char*)d_ws;
    // region0 [0, 4MB): d2p (2MB) + idxp (2MB); reused for gemm partials after enc_finish
    float* d2p     = (float*)ws;
    int*   idxp    = (int*)(ws + (size_t)NCH * B_ * K_ * 4);
    float* partial = (float*)ws;
    float* bpsT    = (float*)(ws + (size_t)4 * 1024 * 1024);   // 1MB
    float* h1T     = (float*)(ws + (size_t)5 * 1024 * 1024);   // 64KB
    float* h2T     = (float*)(ws + (size_t)5 * 1024 * 1024 + 64 * 1024); // 32KB

    // --- BPS encode ---
    enc_partial<<<dim3(K_ / KTB, B_, NCH), 256, 0, stream>>>(pc, basis, d2p, idxp);
    enc_finish<<<(B_ * K_) / 256, 256, 0, stream>>>(pc, basis, d2p, idxp, bps, bpsT);

    // --- MLP ---
    // L1: [16,16384] @ [16384,1024], 32 i-chunks of 512
    mlp_gemm<<<dim3(H1_ / 128, 32), 128, 0, stream>>>(bpsT, W1, partial, H1_, 512);
    mlp_reduce<<<(H1_ * 16) / 256, 256, 0, stream>>>(partial, b1, h1T, nullptr, H1_, 32, 1);
    // L2: [16,1024] @ [1024,512], 16 i-chunks of 64
    mlp_gemm<<<dim3(H2_ / 128, 16), 128, 0, stream>>>(h1T, W2, partial, H2_, 64);
    mlp_reduce<<<(H2_ * 16) / 256, 256, 0, stream>>>(partial, b2, h2T, nullptr, H2_, 16, 1);
    // L3: [16,512] @ [512,256], 16 i-chunks of 32
    mlp_gemm<<<dim3(OUT_ / 128, 16), 128, 0, stream>>>(h2T, W3, partial, OUT_, 32);
    mlp_reduce<<<(OUT_ * 16) / 256, 256, 0, stream>>>(partial, b3, nullptr, gfeat, OUT_, 16, 0);
}

// Round 2
// 265.255 us; speedup vs baseline: 1.1573x; 1.1573x over previous
//
#include <hip/hip_runtime.h>

#define LEAKY_SLOPE 0.2f

constexpr int B_   = 16;
constexpr int N_   = 4096;
constexpr int K_   = 4096;
constexpr int IN_  = 16384;   // K + 3K
constexpr int H1_  = 1024;
constexpr int H2_  = 512;
constexpr int OUT_ = 256;

// encode tiling
constexpr int NCH = 8;
constexpr int NPC = N_ / NCH;   // 512 points -> 8KB LDS
constexpr int KPT = 8;          // k per thread (1 ds_read serves 8 k's)
constexpr int KTB = 256 * KPT;  // 2048 k per block

// -------------------------------------------------------------------------
// Kernel 1: per-(batch, k-tile, n-chunk) partial argmin of d2.
// d2 mirrors numpy: d2 = (bn + pn) - 2*cross, cross = fma chain over d.
// -------------------------------------------------------------------------
__global__ __launch_bounds__(256) void enc_partial(
    const float* __restrict__ pc, const float* __restrict__ basis,
    float* __restrict__ d2p, int* __restrict__ idxp)
{
#pragma clang fp contract(off)
    __shared__ float4 pts[NPC];
    const int kt = blockIdx.x;   // k-tile
    const int b  = blockIdx.y;   // batch
    const int c  = blockIdx.z;   // n-chunk
    const int n0 = c * NPC;

    const float* pcb = pc + ((size_t)b * N_ + n0) * 3;
    for (int n = threadIdx.x; n < NPC; n += 256) {
        float x = pcb[n * 3 + 0];
        float y = pcb[n * 3 + 1];
        float z = pcb[n * 3 + 2];
        float pn = (x * x + y * y) + z * z;   // numpy order, no fma
        pts[n] = make_float4(x, y, z, pn);
    }
    __syncthreads();

    const int k0 = kt * KTB + (int)threadIdx.x;
    float bx[KPT], by[KPT], bz[KPT], bn[KPT], best[KPT];
    int   bi[KPT];
#pragma unroll
    for (int q = 0; q < KPT; ++q) {
        int k = k0 + q * 256;
        bx[q] = basis[k * 3 + 0];
        by[q] = basis[k * 3 + 1];
        bz[q] = basis[k * 3 + 2];
        bn[q] = (bx[q] * bx[q] + by[q] * by[q]) + bz[q] * bz[q];
        best[q] = 3.4028235e38f;
        bi[q] = 0;
    }

#pragma unroll 2
    for (int n = 0; n < NPC; ++n) {
        float4 p = pts[n];
#pragma unroll
        for (int q = 0; q < KPT; ++q) {
            float cr = __builtin_fmaf(bz[q], p.z,
                        __builtin_fmaf(by[q], p.y, bx[q] * p.x));
            float t  = bn[q] + p.w;
            float d2 = __builtin_fmaf(-2.0f, cr, t);   // == t - 2*cr (2*cr exact)
            if (d2 < best[q]) { best[q] = d2; bi[q] = n0 + n; }  // strict < : first-min
        }
    }

#pragma unroll
    for (int q = 0; q < KPT; ++q) {
        int g = b * K_ + (k0 + q * 256);
        d2p[(size_t)c * (B_ * K_) + g]  = best[q];
        idxp[(size_t)c * (B_ * K_) + g] = bi[q];
    }
}

// -------------------------------------------------------------------------
// Kernel 2: combine chunk partials (ascending chunk, strict <), gather
// nearest point, write bps feature (d_out) and transposed bpsT[i][16].
// -------------------------------------------------------------------------
__global__ __launch_bounds__(256) void enc_finish(
    const float* __restrict__ pc, const float* __restrict__ basis,
    const float* __restrict__ d2p, const int* __restrict__ idxp,
    float* __restrict__ bps_out, float* __restrict__ bpsT)
{
#pragma clang fp contract(off)
    const int t = blockIdx.x * 256 + (int)threadIdx.x;   // 0 .. B*K-1
    const int b = t >> 12;
    const int k = t & (K_ - 1);

    float best = d2p[t];
    int   bi   = idxp[t];
    for (int c = 1; c < NCH; ++c) {
        float d = d2p[(size_t)c * (B_ * K_) + t];
        if (d < best) { best = d; bi = idxp[(size_t)c * (B_ * K_) + t]; }
    }

    const float* p = pc + ((size_t)b * N_ + bi) * 3;
    float dx = p[0] - basis[k * 3 + 0];
    float dy = p[1] - basis[k * 3 + 1];
    float dz = p[2] - basis[k * 3 + 2];
    float dist = sqrtf((dx * dx + dy * dy) + dz * dz);

    float* row = bps_out + (size_t)b * IN_;
    row[k]              = dist;
    row[K_ + 3 * k + 0] = dx;
    row[K_ + 3 * k + 1] = dy;
    row[K_ + 3 * k + 2] = dz;

    bpsT[(size_t)k * B_ + b]                = dist;
    bpsT[(size_t)(K_ + 3 * k + 0) * B_ + b] = dx;
    bpsT[(size_t)(K_ + 3 * k + 1) * B_ + b] = dy;
    bpsT[(size_t)(K_ + 3 * k + 2) * B_ + b] = dz;
}

// -------------------------------------------------------------------------
// MLP GEMM v2: block = 256 thr = 4 waves. Wave w -> batches 4w..4w+3
// (A-fragment wave-uniform -> s_load). Lane l -> 4 consecutive cols
// (float4 W load, 1024 B/wave coalesced). 64 k-chunks -> partials.
// partial layout: [chunk][batch(16)][NCOLS]
// -------------------------------------------------------------------------
template<int ILEN, int NCOLS>
__global__ __launch_bounds__(256) void mlp_gemm(
    const float* __restrict__ AT, const float* __restrict__ W,
    float* __restrict__ part)
{
    const int lane = (int)threadIdx.x & 63;
    const int wg   = __builtin_amdgcn_readfirstlane((int)threadIdx.x >> 6);
    const int j0   = blockIdx.x * 256 + lane * 4;
    const int i0   = blockIdx.y * ILEN;

    float acc[4][4];
#pragma unroll
    for (int b = 0; b < 4; ++b)
#pragma unroll
        for (int c = 0; c < 4; ++c) acc[b][c] = 0.0f;

    const float* Arow = AT + 4 * wg;   // wave-uniform base

#pragma unroll 8
    for (int i = 0; i < ILEN; ++i) {
        const float4 wv = *(const float4*)(W + (size_t)(i0 + i) * NCOLS + j0);
        const float4 av = *(const float4*)(Arow + (size_t)(i0 + i) * 16);
        acc[0][0] = __builtin_fmaf(av.x, wv.x, acc[0][0]);
        acc[0][1] = __builtin_fmaf(av.x, wv.y, acc[0][1]);
        acc[0][2] = __builtin_fmaf(av.x, wv.z, acc[0][2]);
        acc[0][3] = __builtin_fmaf(av.x, wv.w, acc[0][3]);
        acc[1][0] = __builtin_fmaf(av.y, wv.x, acc[1][0]);
        acc[1][1] = __builtin_fmaf(av.y, wv.y, acc[1][1]);
        acc[1][2] = __builtin_fmaf(av.y, wv.z, acc[1][2]);
        acc[1][3] = __builtin_fmaf(av.y, wv.w, acc[1][3]);
        acc[2][0] = __builtin_fmaf(av.z, wv.x, acc[2][0]);
        acc[2][1] = __builtin_fmaf(av.z, wv.y, acc[2][1]);
        acc[2][2] = __builtin_fmaf(av.z, wv.z, acc[2][2]);
        acc[2][3] = __builtin_fmaf(av.z, wv.w, acc[2][3]);
        acc[3][0] = __builtin_fmaf(av.w, wv.x, acc[3][0]);
        acc[3][1] = __builtin_fmaf(av.w, wv.y, acc[3][1]);
        acc[3][2] = __builtin_fmaf(av.w, wv.z, acc[3][2]);
        acc[3][3] = __builtin_fmaf(av.w, wv.w, acc[3][3]);
    }

#pragma unroll
    for (int b = 0; b < 4; ++b) {
        float4* dst = (float4*)(part +
            ((size_t)(blockIdx.y * 16 + 4 * wg + b) * NCOLS + j0));
        *dst = make_float4(acc[b][0], acc[b][1], acc[b][2], acc[b][3]);
    }
}

// -------------------------------------------------------------------------
// Reduce partials (ascending chunk) + bias + optional leaky.
// outT[col*16+batch] for next layer's AT; out_rm[batch*NCOLS+col] for final.
// -------------------------------------------------------------------------
__global__ __launch_bounds__(256) void mlp_reduce(
    const float* __restrict__ part, const float* __restrict__ bias,
    float* __restrict__ outT, float* __restrict__ out_rm,
    int Ncols, int nchunks, int do_leaky)
{
    const int p = blockIdx.x * 256 + (int)threadIdx.x;   // batch*Ncols + col
    const int total = Ncols * 16;
    float s = 0.0f;
    for (int c = 0; c < nchunks; ++c) s += part[(size_t)c * total + p];
    const int col   = p % Ncols;
    const int batch = p / Ncols;
    s += bias[col];
    if (do_leaky) s = (s >= 0.0f) ? s : LEAKY_SLOPE * s;
    if (outT)   outT[(size_t)col * 16 + batch] = s;
    if (out_rm) out_rm[(size_t)batch * Ncols + col] = s;
}

// -------------------------------------------------------------------------
extern "C" void kernel_launch(void* const* d_in, const int* in_sizes, int n_in,
                              void* d_out, int out_size, void* d_ws, size_t ws_size,
                              hipStream_t stream)
{
    const float* pc    = (const float*)d_in[0];
    const float* basis = (const float*)d_in[1];
    const float* W1    = (const float*)d_in[2];
    const float* b1    = (const float*)d_in[3];
    const float* W2    = (const float*)d_in[4];
    const float* b2    = (const float*)d_in[5];
    const float* W3    = (const float*)d_in[6];
    const float* b3    = (const float*)d_in[7];

    float* out   = (float*)d_out;
    float* gfeat = out;                 // [16][256]
    float* bps   = out + B_ * OUT_;     // [16][16384]

    char* ws = (char*)d_ws;
    // [0,4MB): d2p(2MB)+idxp(2MB), reused as gemm partials (<=4MB) after enc
    float* d2p     = (float*)ws;
    int*   idxp    = (int*)(ws + (size_t)NCH * B_ * K_ * 4);
    float* partial = (float*)ws;
    float* bpsT    = (float*)(ws + (size_t)4 * 1024 * 1024);   // 1MB
    float* h1T     = (float*)(ws + (size_t)5 * 1024 * 1024);   // 64KB
    float* h2T     = (float*)(ws + (size_t)5 * 1024 * 1024 + 64 * 1024); // 32KB

    // --- BPS encode ---
    enc_partial<<<dim3(K_ / KTB, B_, NCH), 256, 0, stream>>>(pc, basis, d2p, idxp);
    enc_finish<<<(B_ * K_) / 256, 256, 0, stream>>>(pc, basis, d2p, idxp, bps, bpsT);

    // --- MLP ---
    // L1: [16,16384]@[16384,1024]; 64 chunks x ILEN=256; partial = 4MB exactly
    mlp_gemm<256, 1024><<<dim3(4, 64), 256, 0, stream>>>(bpsT, W1, partial);
    mlp_reduce<<<(H1_ * 16) / 256, 256, 0, stream>>>(partial, b1, h1T, nullptr, H1_, 64, 1);
    // L2: [16,1024]@[1024,512]; 64 chunks x ILEN=16; partial = 2MB
    mlp_gemm<16, 512><<<dim3(2, 64), 256, 0, stream>>>(h1T, W2, partial);
    mlp_reduce<<<(H2_ * 16) / 256, 256, 0, stream>>>(partial, b2, h2T, nullptr, H2_, 64, 1);
    // L3: [16,512]@[512,256]; 64 chunks x ILEN=8; partial = 1MB
    mlp_gemm<8, 256><<<dim3(1, 64), 256, 0, stream>>>(h2T, W3, partial);
    mlp_reduce<<<(OUT_ * 16) / 256, 256, 0, stream>>>(partial, b3, nullptr, gfeat, OUT_, 64, 0);
}

// Round 3
// 230.681 us; speedup vs baseline: 1.3308x; 1.1499x over previous
//
#include <hip/hip_runtime.h>

#define LEAKY_SLOPE 0.2f

constexpr int B_   = 16;
constexpr int N_   = 4096;
constexpr int K_   = 4096;
constexpr int IN_  = 16384;   // K + 3K
constexpr int H1_  = 1024;
constexpr int H2_  = 512;
constexpr int OUT_ = 256;

// encode tiling: 16 n-chunks x 256 points (4KB LDS), 4 k per thread
constexpr int NCH = 16;
constexpr int NPC = N_ / NCH;   // 256
constexpr int KPT = 4;
constexpr int KTB = 256 * KPT;  // 1024 k per block -> grid.x = 4

// -------------------------------------------------------------------------
// Kernel 1: per-(k, batch, n-chunk) partial argmin of d2, folded globally
// via u64 atomicMin on packed (orderable_d2_bits << 32 | n).
// d2 mirrors numpy: d2 = (bn + pn) - 2*cross, cross = fma chain over d.
// min over packed = (min d2, then min n) = numpy first-argmin.
// -------------------------------------------------------------------------
__global__ __launch_bounds__(256) void enc_partial(
    const float* __restrict__ pc, const float* __restrict__ basis,
    unsigned long long* __restrict__ packed)
{
#pragma clang fp contract(off)
    __shared__ float4 pts[NPC];
    const int kt = blockIdx.x;   // k-tile
    const int b  = blockIdx.y;   // batch
    const int c  = blockIdx.z;   // n-chunk
    const int n0 = c * NPC;

    const float* pcb = pc + ((size_t)b * N_ + n0) * 3;
    {
        int n = (int)threadIdx.x;          // 256 threads, 256 points
        float x = pcb[n * 3 + 0];
        float y = pcb[n * 3 + 1];
        float z = pcb[n * 3 + 2];
        pts[n] = make_float4(x, y, z, (x * x + y * y) + z * z); // numpy order
    }
    __syncthreads();

    const int k0 = kt * KTB + (int)threadIdx.x;
    float bx[KPT], by[KPT], bz[KPT], bn[KPT], best[KPT];
    int   bi[KPT];
#pragma unroll
    for (int q = 0; q < KPT; ++q) {
        int k = k0 + q * 256;
        bx[q] = basis[k * 3 + 0];
        by[q] = basis[k * 3 + 1];
        bz[q] = basis[k * 3 + 2];
        bn[q] = (bx[q] * bx[q] + by[q] * by[q]) + bz[q] * bz[q];
        best[q] = 3.4028235e38f;
        bi[q] = 0;
    }

#pragma unroll 2
    for (int n = 0; n < NPC; ++n) {
        float4 p = pts[n];
#pragma unroll
        for (int q = 0; q < KPT; ++q) {
            float cr = __builtin_fmaf(bz[q], p.z,
                        __builtin_fmaf(by[q], p.y, bx[q] * p.x));
            float t  = bn[q] + p.w;
            float d2 = __builtin_fmaf(-2.0f, cr, t);   // == t - 2*cr (2*cr exact)
            if (d2 < best[q]) { best[q] = d2; bi[q] = n0 + n; }  // strict <
        }
    }

#pragma unroll
    for (int q = 0; q < KPT; ++q) {
        // monotone map float -> u32 (handles negative d2 from rounding)
        unsigned u = __float_as_uint(best[q]);
        u = (u & 0x80000000u) ? ~u : (u | 0x80000000u);
        unsigned long long v = ((unsigned long long)u << 32) | (unsigned)bi[q];
        atomicMin(&packed[(size_t)b * K_ + (k0 + q * 256)], v);
    }
}

// -------------------------------------------------------------------------
// Kernel 2: unpack argmin index, gather nearest point, write bps feature
// (d_out) and transposed bpsT[i][16] for the GEMM.
// -------------------------------------------------------------------------
__global__ __launch_bounds__(256) void enc_finish(
    const float* __restrict__ pc, const float* __restrict__ basis,
    const unsigned long long* __restrict__ packed,
    float* __restrict__ bps_out, float* __restrict__ bpsT)
{
#pragma clang fp contract(off)
    const int t = blockIdx.x * 256 + (int)threadIdx.x;   // 0 .. B*K-1
    const int b = t >> 12;
    const int k = t & (K_ - 1);

    const int bi = (int)(unsigned)(packed[t] & 0xffffffffull);

    const float* p = pc + ((size_t)b * N_ + bi) * 3;
    float dx = p[0] - basis[k * 3 + 0];
    float dy = p[1] - basis[k * 3 + 1];
    float dz = p[2] - basis[k * 3 + 2];
    float dist = sqrtf((dx * dx + dy * dy) + dz * dz);

    float* row = bps_out + (size_t)b * IN_;
    row[k]              = dist;
    row[K_ + 3 * k + 0] = dx;
    row[K_ + 3 * k + 1] = dy;
    row[K_ + 3 * k + 2] = dz;

    bpsT[(size_t)k * B_ + b]                = dist;
    bpsT[(size_t)(K_ + 3 * k + 0) * B_ + b] = dx;
    bpsT[(size_t)(K_ + 3 * k + 1) * B_ + b] = dy;
    bpsT[(size_t)(K_ + 3 * k + 2) * B_ + b] = dz;
}

// -------------------------------------------------------------------------
// MLP GEMM v3: block = 4 waves; wave w -> batches 4w..4w+3 (A wave-uniform
// -> s_load_dwordx4); lane -> ONE column (float W load, 256B/wave
// coalesced). grid = (NCOLS/64 colblocks, chunks). 4 waves/SIMD for L1.
// partial layout: [chunk][batchrow(16)][NCOLS]
// -------------------------------------------------------------------------
template<int ILEN, int NCOLS>
__global__ __launch_bounds__(256) void mlp_gemm(
    const float* __restrict__ AT, const float* __restrict__ W,
    float* __restrict__ part)
{
    const int lane = (int)threadIdx.x & 63;
    const int wg   = __builtin_amdgcn_readfirstlane((int)threadIdx.x >> 6);
    const int j    = blockIdx.x * 64 + lane;
    const int i0   = blockIdx.y * ILEN;

    float a0 = 0.0f, a1 = 0.0f, a2 = 0.0f, a3 = 0.0f;
    const float* Arow = AT + 4 * wg;   // wave-uniform base

#pragma unroll 8
    for (int i = 0; i < ILEN; ++i) {
        float  wv = W[(size_t)(i0 + i) * NCOLS + j];
        float4 av = *(const float4*)(Arow + (size_t)(i0 + i) * 16);
        a0 = __builtin_fmaf(av.x, wv, a0);
        a1 = __builtin_fmaf(av.y, wv, a1);
        a2 = __builtin_fmaf(av.z, wv, a2);
        a3 = __builtin_fmaf(av.w, wv, a3);
    }

    const size_t base = (size_t)blockIdx.y * 16 + 4 * wg;
    part[(base + 0) * NCOLS + j] = a0;
    part[(base + 1) * NCOLS + j] = a1;
    part[(base + 2) * NCOLS + j] = a2;
    part[(base + 3) * NCOLS + j] = a3;
}

// -------------------------------------------------------------------------
// Reduce partials (ascending chunk) + bias + optional leaky.
// outT[col*16+batch] feeds next layer's AT; out_rm[batch*NCOLS+col] final.
// -------------------------------------------------------------------------
__global__ __launch_bounds__(256) void mlp_reduce(
    const float* __restrict__ part, const float* __restrict__ bias,
    float* __restrict__ outT, float* __restrict__ out_rm,
    int Ncols, int nchunks, int do_leaky)
{
    const int p = blockIdx.x * 256 + (int)threadIdx.x;   // batch*Ncols + col
    const int total = Ncols * 16;
    float s = 0.0f;
    for (int c = 0; c < nchunks; ++c) s += part[(size_t)c * total + p];
    const int col   = p % Ncols;
    const int batch = p / Ncols;
    s += bias[col];
    if (do_leaky) s = (s >= 0.0f) ? s : LEAKY_SLOPE * s;
    if (outT)   outT[(size_t)col * 16 + batch] = s;
    if (out_rm) out_rm[(size_t)batch * Ncols + col] = s;
}

// -------------------------------------------------------------------------
extern "C" void kernel_launch(void* const* d_in, const int* in_sizes, int n_in,
                              void* d_out, int out_size, void* d_ws, size_t ws_size,
                              hipStream_t stream)
{
    const float* pc    = (const float*)d_in[0];
    const float* basis = (const float*)d_in[1];
    const float* W1    = (const float*)d_in[2];
    const float* b1    = (const float*)d_in[3];
    const float* W2    = (const float*)d_in[4];
    const float* b2    = (const float*)d_in[5];
    const float* W3    = (const float*)d_in[6];
    const float* b3    = (const float*)d_in[7];

    float* out   = (float*)d_out;
    float* gfeat = out;                 // [16][256]
    float* bps   = out + B_ * OUT_;     // [16][16384]

    char* ws = (char*)d_ws;
    unsigned long long* packed = (unsigned long long*)ws;               // 512KB
    float* partial = (float*)(ws + (size_t)1 * 1024 * 1024);            // <=4MB
    float* bpsT    = (float*)(ws + (size_t)5 * 1024 * 1024);            // 1MB
    float* h1T     = (float*)(ws + (size_t)6 * 1024 * 1024);            // 64KB
    float* h2T     = (float*)(ws + (size_t)6 * 1024 * 1024 + 64 * 1024);// 32KB

    // --- BPS encode ---
    hipMemsetAsync(packed, 0xFF, (size_t)B_ * K_ * 8, stream);   // +inf keys
    enc_partial<<<dim3(K_ / KTB, B_, NCH), 256, 0, stream>>>(pc, basis, packed);
    enc_finish<<<(B_ * K_) / 256, 256, 0, stream>>>(pc, basis, packed, bps, bpsT);

    // --- MLP ---
    // L1: [16,16384]@[16384,1024]; 16 colblocks x 64 chunks (ILEN=256); 4MB partial
    mlp_gemm<256, 1024><<<dim3(16, 64), 256, 0, stream>>>(bpsT, W1, partial);
    mlp_reduce<<<(H1_ * 16) / 256, 256, 0, stream>>>(partial, b1, h1T, nullptr, H1_, 64, 1);
    // L2: [16,1024]@[1024,512]; 8 colblocks x 64 chunks (ILEN=16); 2MB partial
    mlp_gemm<16, 512><<<dim3(8, 64), 256, 0, stream>>>(h1T, W2, partial);
    mlp_reduce<<<(H2_ * 16) / 256, 256, 0, stream>>>(partial, b2, h2T, nullptr, H2_, 64, 1);
    // L3: [16,512]@[512,256]; 4 colblocks x 64 chunks (ILEN=8); 1MB partial
    mlp_gemm<8, 256><<<dim3(4, 64), 256, 0, stream>>>(h2T, W3, partial);
    mlp_reduce<<<(OUT_ * 16) / 256, 256, 0, stream>>>(partial, b3, nullptr, gfeat, OUT_, 64, 0);
}